// Round 2
// baseline (957.132 us; speedup 1.0000x reference)
//
#include <hip/hip_runtime.h>
#include <math.h>

// ---------------------------------------------------------------------------
#define B_ROWS   8192
#define NZ       100
#define NC       2
#define H1       256
#define H2       64
#define FEATN    8192
#define FDIM     1024
#define RROWS    16            // rows per k_main block
#define FF       8             // f values per thread
#define CHUNKF   (256 * FF)    // 2048 f per chunk
#define NCHUNK   (FEATN / CHUNKF)  // 4
#define SLABS    64            // row slabs for stats stage 1

// ---------------------------------------------------------------------------
// JAX threefry2x32, partitionable, key=(0,42), counter=(0, flat)
__device__ __forceinline__ unsigned rotl32(unsigned v, int r) {
    return (v << r) | (v >> (32 - r));
}
__device__ __forceinline__ unsigned threefry_bits(unsigned lo) {
    const unsigned ks0 = 0u, ks1 = 42u, ks2 = 0x1BD11BDAu ^ 42u;
    unsigned x0 = 0u + ks0;
    unsigned x1 = lo + ks1;
#define TF_R4(a,b,c,d) \
    x0 += x1; x1 = rotl32(x1,a); x1 ^= x0; \
    x0 += x1; x1 = rotl32(x1,b); x1 ^= x0; \
    x0 += x1; x1 = rotl32(x1,c); x1 ^= x0; \
    x0 += x1; x1 = rotl32(x1,d); x1 ^= x0;
    TF_R4(13,15,26,6);  x0 += ks1; x1 += ks2 + 1u;
    TF_R4(17,29,16,24); x0 += ks2; x1 += ks0 + 2u;
    TF_R4(13,15,26,6);  x0 += ks0; x1 += ks1 + 3u;
    TF_R4(17,29,16,24); x0 += ks1; x1 += ks2 + 4u;
    TF_R4(13,15,26,6);  x0 += ks2; x1 += ks0 + 5u;
#undef TF_R4
    return x0 ^ x1;
}
__device__ __forceinline__ float gumbel_g(unsigned flat) {
    unsigned bits = threefry_bits(flat);
    float u  = __uint_as_float((bits >> 9) | 0x3f800000u) - 1.0f;
    float U  = 0.001f * u;
    float t1 = U + 0.001f;
    float L1 = (float)log((double)t1);
    float A  = 0.001f - L1;
    float L2 = (float)log((double)A);
    return -L2;
}

// ---------------------------------------------------------------------------
// K1: a1 = concat(x,y) @ W1 + b1, fp64 accumulate
__global__ __launch_bounds__(256) void k_a1(
    const float* __restrict__ x, const float* __restrict__ y,
    const float* __restrict__ W1, const float* __restrict__ b1,
    float* __restrict__ a1)
{
    const int j  = threadIdx.x;
    const int b0 = blockIdx.x * 8;
    double acc[8];
#pragma unroll
    for (int r = 0; r < 8; ++r) acc[r] = 0.0;
    for (int i = 0; i < NZ; ++i) {
        float w = W1[i * H1 + j];
#pragma unroll
        for (int r = 0; r < 8; ++r)
            acc[r] += (double)x[(b0 + r) * NZ + i] * (double)w;
    }
#pragma unroll
    for (int i = 0; i < NC; ++i) {
        float w = W1[(NZ + i) * H1 + j];
#pragma unroll
        for (int r = 0; r < 8; ++r)
            acc[r] += (double)y[(b0 + r) * NC + i] * (double)w;
    }
    double bb = (double)b1[j];
#pragma unroll
    for (int r = 0; r < 8; ++r)
        a1[(b0 + r) * H1 + j] = (float)(acc[r] + bb);
}

// ---------------------------------------------------------------------------
// BN stats, coalesced 2-stage. Stage 1: per-slab per-column fp64 partials.
__global__ __launch_bounds__(256) void k_stats1(
    const float* __restrict__ A, int ncol,
    double* __restrict__ p1, double* __restrict__ p2)
{
    const int g = blockIdx.x, t = threadIdx.x;
    const int c    = t & (ncol - 1);
    const int rsub = t / ncol;
    const int rpt  = 256 / ncol;
    const int rows = B_ROWS / SLABS;          // 128
    const float* base = A + (size_t)g * rows * ncol;
    double s = 0.0, s2 = 0.0;
    for (int r = rsub; r < rows; r += rpt) {
        double v = (double)base[r * ncol + c];   // coalesced
        s += v; s2 += v * v;
    }
    __shared__ double ls[256], ls2[256];
    ls[t] = s; ls2[t] = s2;
    __syncthreads();
    if (rsub == 0) {
        for (int k = 1; k < rpt; ++k) { s += ls[k * ncol + c]; s2 += ls2[k * ncol + c]; }
        p1[g * ncol + c] = s;
        p2[g * ncol + c] = s2;
    }
}

// Stage 2: reduce SLABS partials per column; fold gamma/beta into scale/shift.
__global__ __launch_bounds__(64) void k_stats2(
    const double* __restrict__ p1, const double* __restrict__ p2, int ncol,
    const float* __restrict__ gamma, const float* __restrict__ beta,
    float* __restrict__ scale, float* __restrict__ shift)
{
    const int j = blockIdx.x, t = threadIdx.x;   // t over 64 slabs (one wave)
    double s  = p1[(size_t)t * ncol + j];
    double s2 = p2[(size_t)t * ncol + j];
#pragma unroll
    for (int off = 32; off; off >>= 1) {
        s  += __shfl_xor(s, off);
        s2 += __shfl_xor(s2, off);
    }
    if (t == 0) {
        double mean = s * (1.0 / B_ROWS);
        double var  = s2 * (1.0 / B_ROWS) - mean * mean;
        double rstd = 1.0 / sqrt(var + 1e-5);
        double sc   = (double)gamma[j] * rstd;
        scale[j] = (float)sc;
        shift[j] = (float)((double)beta[j] - mean * sc);
    }
}

// ---------------------------------------------------------------------------
// K3: a2 = relu(bn(a1)) @ W2 + b2, fp64 accumulate
__global__ __launch_bounds__(256) void k_a2(
    const float* __restrict__ a1,
    const float* __restrict__ sc1, const float* __restrict__ sh1,
    const float* __restrict__ W2, const float* __restrict__ b2,
    float* __restrict__ a2)
{
    const int t  = threadIdx.x;
    const int k  = t & 63;
    const int rr = t >> 6;
    const int b  = blockIdx.x * 4 + rr;
    double acc = 0.0;
    for (int j = 0; j < H1; ++j) {
        float h = fmaxf(fmaf(a1[b * H1 + j], sc1[j], sh1[j]), 0.0f);
        acc += (double)h * (double)W2[j * H2 + k];
    }
    a2[b * H2 + k] = (float)(acc + (double)b2[k]);
}

// ---------------------------------------------------------------------------
// K5: pass A = rowmax of logits with per-(chunk,wave,row) maxima;
//     pass B = recompute only qualifying cells, gumbel-argmax; gather codebook.
__global__ __launch_bounds__(256, 2) void k_main(
    const float* __restrict__ a2,
    const float* __restrict__ sc2, const float* __restrict__ sh2,
    const float* __restrict__ W3, const float* __restrict__ b3,
    const float* __restrict__ codebook, float* __restrict__ out)
{
    const int t    = threadIdx.x;
    const int wv   = t >> 6;
    const int lane = t & 63;
    const int b0   = blockIdx.x * RROWS;

    __shared__ __align__(16) float h2T[64][RROWS];   // [j][r]
    __shared__ float cm[NCHUNK][RROWS][4];           // per-(chunk,row,wave) max
    __shared__ float thrS[RROWS];
    __shared__ float redS[RROWS][4];
    __shared__ int   redI[RROWS][4];
    __shared__ int   rowInd[RROWS];

    // h2 = relu(bn(a2)) for our rows
    for (int q = t; q < RROWS * 64; q += 256) {
        int r = q >> 6, j = q & 63;
        float v = a2[(b0 + r) * H2 + j];
        h2T[j][r] = fmaxf(fmaf(v, sc2[j], sh2[j]), 0.0f);
    }
    __syncthreads();

    // ---- Pass A ----
    for (int fc = 0; fc < NCHUNK; ++fc) {
        const int fbase = fc * CHUNKF + t * FF;
        const float4 bbA = *(const float4*)(b3 + fbase);
        const float4 bbB = *(const float4*)(b3 + fbase + 4);
        float acc[RROWS][FF];
#pragma unroll
        for (int r = 0; r < RROWS; ++r) {
            acc[r][0] = bbA.x; acc[r][1] = bbA.y; acc[r][2] = bbA.z; acc[r][3] = bbA.w;
            acc[r][4] = bbB.x; acc[r][5] = bbB.y; acc[r][6] = bbB.z; acc[r][7] = bbB.w;
        }
        const float* wrow = W3 + fbase;
#pragma unroll 2
        for (int j = 0; j < 64; ++j) {
            const float4 wA = *(const float4*)(wrow);
            const float4 wB = *(const float4*)(wrow + 4);
            const float4* hp = (const float4*)(&h2T[j][0]);
            const float4 h0 = hp[0], h1 = hp[1], h2 = hp[2], h3 = hp[3];
            const float hv[16] = {h0.x,h0.y,h0.z,h0.w, h1.x,h1.y,h1.z,h1.w,
                                  h2.x,h2.y,h2.z,h2.w, h3.x,h3.y,h3.z,h3.w};
#pragma unroll
            for (int r = 0; r < RROWS; ++r) {
                const float hr = hv[r];
                acc[r][0] = fmaf(hr, wA.x, acc[r][0]);
                acc[r][1] = fmaf(hr, wA.y, acc[r][1]);
                acc[r][2] = fmaf(hr, wA.z, acc[r][2]);
                acc[r][3] = fmaf(hr, wA.w, acc[r][3]);
                acc[r][4] = fmaf(hr, wB.x, acc[r][4]);
                acc[r][5] = fmaf(hr, wB.y, acc[r][5]);
                acc[r][6] = fmaf(hr, wB.z, acc[r][6]);
                acc[r][7] = fmaf(hr, wB.w, acc[r][7]);
            }
            wrow += FEATN;
        }
        // per-(chunk,row) wave max
#pragma unroll
        for (int r = 0; r < RROWS; ++r) {
            float m = acc[r][0];
#pragma unroll
            for (int q = 1; q < FF; ++q) m = fmaxf(m, acc[r][q]);
#pragma unroll
            for (int off = 32; off; off >>= 1) m = fmaxf(m, __shfl_xor(m, off));
            if (lane == 0) cm[fc][r][wv] = m;
        }
    }
    __syncthreads();
    if (t < RROWS) {
        float m = -1e30f;
        for (int fc = 0; fc < NCHUNK; ++fc)
            for (int w = 0; w < 4; ++w) m = fmaxf(m, cm[fc][t][w]);
        thrS[t] = m - 0.1068f;    // gumbel range 0.10581 + slack
    }
    __syncthreads();

    // ---- Pass B: recompute only qualifying (chunk, wave) cells ----
    float bS[RROWS]; int bI[RROWS];
#pragma unroll
    for (int r = 0; r < RROWS; ++r) { bS[r] = -1e30f; bI[r] = 0x7fffffff; }

    for (int fc = 0; fc < NCHUNK; ++fc) {
        unsigned qmask = 0;
#pragma unroll
        for (int r = 0; r < RROWS; ++r)
            if (cm[fc][r][wv] >= thrS[r]) qmask |= (1u << r);
        if (qmask == 0) continue;                   // wave-uniform skip

        const int fbase = fc * CHUNKF + t * FF;
        const float4 bbA = *(const float4*)(b3 + fbase);
        const float4 bbB = *(const float4*)(b3 + fbase + 4);
        float acc[RROWS][FF];
#pragma unroll
        for (int r = 0; r < RROWS; ++r) {
            if (qmask & (1u << r)) {
                acc[r][0] = bbA.x; acc[r][1] = bbA.y; acc[r][2] = bbA.z; acc[r][3] = bbA.w;
                acc[r][4] = bbB.x; acc[r][5] = bbB.y; acc[r][6] = bbB.z; acc[r][7] = bbB.w;
            }
        }
        const float* wrow = W3 + fbase;
        for (int j = 0; j < 64; ++j) {
            const float4 wA = *(const float4*)(wrow);
            const float4 wB = *(const float4*)(wrow + 4);
#pragma unroll
            for (int r = 0; r < RROWS; ++r) {
                if (qmask & (1u << r)) {
                    const float hr = h2T[j][r];
                    acc[r][0] = fmaf(hr, wA.x, acc[r][0]);
                    acc[r][1] = fmaf(hr, wA.y, acc[r][1]);
                    acc[r][2] = fmaf(hr, wA.z, acc[r][2]);
                    acc[r][3] = fmaf(hr, wA.w, acc[r][3]);
                    acc[r][4] = fmaf(hr, wB.x, acc[r][4]);
                    acc[r][5] = fmaf(hr, wB.y, acc[r][5]);
                    acc[r][6] = fmaf(hr, wB.z, acc[r][6]);
                    acc[r][7] = fmaf(hr, wB.w, acc[r][7]);
                }
            }
            wrow += FEATN;
        }
#pragma unroll
        for (int r = 0; r < RROWS; ++r) {
            if (qmask & (1u << r)) {
#pragma unroll
                for (int q = 0; q < FF; ++q) {
                    float v = acc[r][q];
                    if (v >= thrS[r]) {
                        unsigned f = (unsigned)(fbase + q);
                        float sc = v + gumbel_g((unsigned)(b0 + r) * (unsigned)FEATN + f);
                        if (sc > bS[r] || (sc == bS[r] && (int)f < bI[r])) {
                            bS[r] = sc; bI[r] = (int)f;
                        }
                    }
                }
            }
        }
    }

    // reduce best (val, idx) across wave, then across waves
#pragma unroll
    for (int r = 0; r < RROWS; ++r) {
        float v = bS[r]; int ix = bI[r];
#pragma unroll
        for (int off = 32; off; off >>= 1) {
            float ov = __shfl_xor(v, off);
            int   oi = __shfl_xor(ix, off);
            if (ov > v || (ov == v && oi < ix)) { v = ov; ix = oi; }
        }
        if (lane == 0) { redS[r][wv] = v; redI[r][wv] = ix; }
    }
    __syncthreads();
    if (t < RROWS) {
        float v = -1e30f; int ix = 0x7fffffff;
        for (int w = 0; w < 4; ++w) {
            float ov = redS[t][w]; int oi = redI[t][w];
            if (ov > v || (ov == v && oi < ix)) { v = ov; ix = oi; }
        }
        rowInd[t] = ix;
    }
    __syncthreads();

    // out[b,:] = codebook[ind,:]   (z_st == one-hot to ~1e-7)
    for (int r = 0; r < RROWS; ++r) {
        const int ind = rowInd[r];
        const float4* src = (const float4*)(codebook + (size_t)ind * FDIM);
        float4*       dst = (float4*)(out + (size_t)(b0 + r) * FDIM);
        dst[t] = src[t];
    }
}

// ---------------------------------------------------------------------------
extern "C" void kernel_launch(void* const* d_in, const int* in_sizes, int n_in,
                              void* d_out, int out_size, void* d_ws, size_t ws_size,
                              hipStream_t stream)
{
    const float* x   = (const float*)d_in[0];
    const float* y   = (const float*)d_in[1];
    const float* W1  = (const float*)d_in[2];
    const float* b1  = (const float*)d_in[3];
    const float* g1  = (const float*)d_in[4];
    const float* be1 = (const float*)d_in[5];
    const float* W2  = (const float*)d_in[6];
    const float* b2  = (const float*)d_in[7];
    const float* g2  = (const float*)d_in[8];
    const float* be2 = (const float*)d_in[9];
    const float* W3  = (const float*)d_in[10];
    const float* b3  = (const float*)d_in[11];
    const float* cb  = (const float*)d_in[12];
    float* out = (float*)d_out;

    float* ws  = (float*)d_ws;
    float* a1  = ws;                          // 8192*256 f32
    float* a2  = a1 + B_ROWS * H1;            // 8192*64 f32
    float* sc1 = a2 + B_ROWS * H2;
    float* sh1 = sc1 + H1;
    float* sc2 = sh1 + H1;
    float* sh2 = sc2 + H2;
    double* p1 = (double*)(sh2 + H2 + 64);    // 64*256 f64 (aligned region)
    double* p2 = p1 + SLABS * H1;             // 64*256 f64

    k_a1    <<<B_ROWS / 8, 256, 0, stream>>>(x, y, W1, b1, a1);
    k_stats1<<<SLABS, 256, 0, stream>>>(a1, H1, p1, p2);
    k_stats2<<<H1, 64, 0, stream>>>(p1, p2, H1, g1, be1, sc1, sh1);
    k_a2    <<<B_ROWS / 4, 256, 0, stream>>>(a1, sc1, sh1, W2, b2, a2);
    k_stats1<<<SLABS, 256, 0, stream>>>(a2, H2, p1, p2);
    k_stats2<<<H2, 64, 0, stream>>>(p1, p2, H2, g2, be2, sc2, sh2);
    k_main  <<<B_ROWS / RROWS, 256, 0, stream>>>(a2, sc2, sh2, W3, b3, cb, out);
}

// Round 4
// 530.735 us; speedup vs baseline: 1.8034x; 1.8034x over previous
//
#include <hip/hip_runtime.h>
#include <math.h>

// ---------------------------------------------------------------------------
#define B_ROWS   8192
#define NZ       100
#define NC       2
#define H1       256
#define H2       64
#define FEATN    8192
#define FDIM     1024
#define RROWS    8             // rows per k_main block (acc = 64 VGPRs, no spill)
#define FF       8             // f values per thread
#define CHUNKF   (256 * FF)    // 2048 f per chunk
#define NCHUNK   (FEATN / CHUNKF)  // 4
#define SLABS    64            // row slabs for stats stage 1

// ---------------------------------------------------------------------------
// JAX threefry2x32, partitionable, key=(0,42), counter=(0, flat)
__device__ __forceinline__ unsigned rotl32(unsigned v, int r) {
    return (v << r) | (v >> (32 - r));
}
__device__ __forceinline__ unsigned threefry_bits(unsigned lo) {
    const unsigned ks0 = 0u, ks1 = 42u, ks2 = 0x1BD11BDAu ^ 42u;
    unsigned x0 = 0u + ks0;
    unsigned x1 = lo + ks1;
#define TF_R4(a,b,c,d) \
    x0 += x1; x1 = rotl32(x1,a); x1 ^= x0; \
    x0 += x1; x1 = rotl32(x1,b); x1 ^= x0; \
    x0 += x1; x1 = rotl32(x1,c); x1 ^= x0; \
    x0 += x1; x1 = rotl32(x1,d); x1 ^= x0;
    TF_R4(13,15,26,6);  x0 += ks1; x1 += ks2 + 1u;
    TF_R4(17,29,16,24); x0 += ks2; x1 += ks0 + 2u;
    TF_R4(13,15,26,6);  x0 += ks0; x1 += ks1 + 3u;
    TF_R4(17,29,16,24); x0 += ks1; x1 += ks2 + 4u;
    TF_R4(13,15,26,6);  x0 += ks2; x1 += ks0 + 5u;
#undef TF_R4
    return x0 ^ x1;
}
__device__ __forceinline__ float gumbel_g(unsigned flat) {
    unsigned bits = threefry_bits(flat);
    float u  = __uint_as_float((bits >> 9) | 0x3f800000u) - 1.0f;
    float U  = 0.001f * u;
    float t1 = U + 0.001f;
    float L1 = (float)log((double)t1);
    float A  = 0.001f - L1;
    float L2 = (float)log((double)A);
    return -L2;
}

// ---------------------------------------------------------------------------
// K1: a1 = concat(x,y) @ W1 + b1, fp64 accumulate
__global__ __launch_bounds__(256) void k_a1(
    const float* __restrict__ x, const float* __restrict__ y,
    const float* __restrict__ W1, const float* __restrict__ b1,
    float* __restrict__ a1)
{
    const int j  = threadIdx.x;
    const int b0 = blockIdx.x * 8;
    double acc[8];
#pragma unroll
    for (int r = 0; r < 8; ++r) acc[r] = 0.0;
    for (int i = 0; i < NZ; ++i) {
        float w = W1[i * H1 + j];
#pragma unroll
        for (int r = 0; r < 8; ++r)
            acc[r] += (double)x[(b0 + r) * NZ + i] * (double)w;
    }
#pragma unroll
    for (int i = 0; i < NC; ++i) {
        float w = W1[(NZ + i) * H1 + j];
#pragma unroll
        for (int r = 0; r < 8; ++r)
            acc[r] += (double)y[(b0 + r) * NC + i] * (double)w;
    }
    double bb = (double)b1[j];
#pragma unroll
    for (int r = 0; r < 8; ++r)
        a1[(b0 + r) * H1 + j] = (float)(acc[r] + bb);
}

// ---------------------------------------------------------------------------
// BN stats, coalesced 2-stage. Stage 1: per-slab per-column fp64 partials.
__global__ __launch_bounds__(256) void k_stats1(
    const float* __restrict__ A, int ncol,
    double* __restrict__ p1, double* __restrict__ p2)
{
    const int g = blockIdx.x, t = threadIdx.x;
    const int c    = t & (ncol - 1);
    const int rsub = t / ncol;
    const int rpt  = 256 / ncol;
    const int rows = B_ROWS / SLABS;          // 128
    const float* base = A + (size_t)g * rows * ncol;
    double s = 0.0, s2 = 0.0;
    for (int r = rsub; r < rows; r += rpt) {
        double v = (double)base[r * ncol + c];   // coalesced
        s += v; s2 += v * v;
    }
    __shared__ double ls[256], ls2[256];
    ls[t] = s; ls2[t] = s2;
    __syncthreads();
    if (rsub == 0) {
        for (int k = 1; k < rpt; ++k) { s += ls[k * ncol + c]; s2 += ls2[k * ncol + c]; }
        p1[g * ncol + c] = s;
        p2[g * ncol + c] = s2;
    }
}

// Stage 2: reduce SLABS partials per column; fold gamma/beta into scale/shift.
__global__ __launch_bounds__(64) void k_stats2(
    const double* __restrict__ p1, const double* __restrict__ p2, int ncol,
    const float* __restrict__ gamma, const float* __restrict__ beta,
    float* __restrict__ scale, float* __restrict__ shift)
{
    const int j = blockIdx.x, t = threadIdx.x;
    double s  = p1[(size_t)t * ncol + j];
    double s2 = p2[(size_t)t * ncol + j];
#pragma unroll
    for (int off = 32; off; off >>= 1) {
        s  += __shfl_xor(s, off);
        s2 += __shfl_xor(s2, off);
    }
    if (t == 0) {
        double mean = s * (1.0 / B_ROWS);
        double var  = s2 * (1.0 / B_ROWS) - mean * mean;
        double rstd = 1.0 / sqrt(var + 1e-5);
        double sc   = (double)gamma[j] * rstd;
        scale[j] = (float)sc;
        shift[j] = (float)((double)beta[j] - mean * sc);
    }
}

// ---------------------------------------------------------------------------
// K3: a2 = relu(bn(a1)) @ W2 + b2, fp64 accumulate
__global__ __launch_bounds__(256) void k_a2(
    const float* __restrict__ a1,
    const float* __restrict__ sc1, const float* __restrict__ sh1,
    const float* __restrict__ W2, const float* __restrict__ b2,
    float* __restrict__ a2)
{
    const int t  = threadIdx.x;
    const int k  = t & 63;
    const int rr = t >> 6;
    const int b  = blockIdx.x * 4 + rr;
    double acc = 0.0;
    for (int j = 0; j < H1; ++j) {
        float h = fmaxf(fmaf(a1[b * H1 + j], sc1[j], sh1[j]), 0.0f);
        acc += (double)h * (double)W2[j * H2 + k];
    }
    a2[b * H2 + k] = (float)(acc + (double)b2[k]);
}

// ---------------------------------------------------------------------------
// One FMA micro-step, kept in a macro so pass A and pass B are bit-identical.
#define FMA8(r) \
    accA[r].x = fmaf(hr, wA.x, accA[r].x); \
    accA[r].y = fmaf(hr, wA.y, accA[r].y); \
    accA[r].z = fmaf(hr, wA.z, accA[r].z); \
    accA[r].w = fmaf(hr, wA.w, accA[r].w); \
    accB[r].x = fmaf(hr, wB.x, accB[r].x); \
    accB[r].y = fmaf(hr, wB.y, accB[r].y); \
    accB[r].z = fmaf(hr, wB.z, accB[r].z); \
    accB[r].w = fmaf(hr, wB.w, accB[r].w);

// K5: pass A = rowmax of logits; pass B = recompute only qualifying
//     (chunk,wave) cells with gumbel; gather codebook row.
__global__ __launch_bounds__(256, 2) void k_main(
    const float* __restrict__ a2,
    const float* __restrict__ sc2, const float* __restrict__ sh2,
    const float* __restrict__ W3, const float* __restrict__ b3,
    const float* __restrict__ codebook, float* __restrict__ out)
{
    const int t    = threadIdx.x;
    const int wv   = t >> 6;
    const int lane = t & 63;
    const int b0   = blockIdx.x * RROWS;

    __shared__ __align__(16) float h2T[64][RROWS];   // [j][r], 2 KB
    __shared__ float cm[NCHUNK][RROWS][4];
    __shared__ float thrS[RROWS];
    __shared__ float redS[RROWS][4];
    __shared__ int   redI[RROWS][4];
    __shared__ int   rowInd[RROWS];

    // h2 = relu(bn(a2)) for our rows — STRIDED: 512 elements, 256 threads
    for (int q = t; q < RROWS * 64; q += 256) {
        int j = q >> 3, r = q & 7;          // j in 0..63, r in 0..7
        float v = a2[(b0 + r) * H2 + j];
        h2T[j][r] = fmaxf(fmaf(v, sc2[j], sh2[j]), 0.0f);
    }
    __syncthreads();

    // ---- Pass A: rowmax of logits ----
    for (int fc = 0; fc < NCHUNK; ++fc) {
        const int fbase = fc * CHUNKF + t * FF;
        const float4 bbA = *(const float4*)(b3 + fbase);
        const float4 bbB = *(const float4*)(b3 + fbase + 4);
        float4 accA[RROWS], accB[RROWS];
#pragma unroll
        for (int r = 0; r < RROWS; ++r) { accA[r] = bbA; accB[r] = bbB; }
        const float* wrow = W3 + fbase;
        for (int j = 0; j < 64; ++j) {
            const float4 wA = *(const float4*)(wrow);
            const float4 wB = *(const float4*)(wrow + 4);
            const float4 h0 = *(const float4*)(&h2T[j][0]);
            const float4 h1 = *(const float4*)(&h2T[j][4]);
            { const float hr = h0.x; FMA8(0) }
            { const float hr = h0.y; FMA8(1) }
            { const float hr = h0.z; FMA8(2) }
            { const float hr = h0.w; FMA8(3) }
            { const float hr = h1.x; FMA8(4) }
            { const float hr = h1.y; FMA8(5) }
            { const float hr = h1.z; FMA8(6) }
            { const float hr = h1.w; FMA8(7) }
            wrow += FEATN;
        }
#pragma unroll
        for (int r = 0; r < RROWS; ++r) {
            float m = fmaxf(fmaxf(fmaxf(accA[r].x, accA[r].y), fmaxf(accA[r].z, accA[r].w)),
                            fmaxf(fmaxf(accB[r].x, accB[r].y), fmaxf(accB[r].z, accB[r].w)));
#pragma unroll
            for (int off = 32; off; off >>= 1) m = fmaxf(m, __shfl_xor(m, off));
            if (lane == 0) cm[fc][r][wv] = m;
        }
    }
    __syncthreads();
    if (t < RROWS) {
        float m = -1e30f;
        for (int fc = 0; fc < NCHUNK; ++fc)
            for (int w = 0; w < 4; ++w) m = fmaxf(m, cm[fc][t][w]);
        thrS[t] = m - 0.1068f;    // gumbel range 0.10581 + fp32 slack
    }
    __syncthreads();

    // ---- Pass B: recompute only qualifying (chunk, wave) cells ----
    float bS[RROWS]; int bI[RROWS];
#pragma unroll
    for (int r = 0; r < RROWS; ++r) { bS[r] = -1e30f; bI[r] = 0; }

    for (int fc = 0; fc < NCHUNK; ++fc) {
        unsigned qmask = 0;
#pragma unroll
        for (int r = 0; r < RROWS; ++r)
            if (cm[fc][r][wv] >= thrS[r]) qmask |= (1u << r);
        if (qmask == 0) continue;                 // wave-uniform skip

        const int fbase = fc * CHUNKF + t * FF;
        const float4 bbA = *(const float4*)(b3 + fbase);
        const float4 bbB = *(const float4*)(b3 + fbase + 4);
        float4 accA[RROWS], accB[RROWS];
#pragma unroll
        for (int r = 0; r < RROWS; ++r) { accA[r] = bbA; accB[r] = bbB; }
        const float* wrow = W3 + fbase;
        for (int j = 0; j < 64; ++j) {
            const float4 wA = *(const float4*)(wrow);
            const float4 wB = *(const float4*)(wrow + 4);
            const float4 h0 = *(const float4*)(&h2T[j][0]);
            const float4 h1 = *(const float4*)(&h2T[j][4]);
            { const float hr = h0.x; FMA8(0) }
            { const float hr = h0.y; FMA8(1) }
            { const float hr = h0.z; FMA8(2) }
            { const float hr = h0.w; FMA8(3) }
            { const float hr = h1.x; FMA8(4) }
            { const float hr = h1.y; FMA8(5) }
            { const float hr = h1.z; FMA8(6) }
            { const float hr = h1.w; FMA8(7) }
            wrow += FEATN;
        }
#pragma unroll
        for (int r = 0; r < RROWS; ++r) {
            if (qmask & (1u << r)) {
                const float th = thrS[r];
                float v0[FF] = {accA[r].x, accA[r].y, accA[r].z, accA[r].w,
                                accB[r].x, accB[r].y, accB[r].z, accB[r].w};
#pragma unroll
                for (int q = 0; q < FF; ++q) {
                    float v = v0[q];
                    if (v >= th) {
                        unsigned f = (unsigned)(fbase + q);
                        float sc = v + gumbel_g((unsigned)(b0 + r) * (unsigned)FEATN + f);
                        // strict >: ties at equal score resolved by processing
                        // order, but exact fp ties across different f are
                        // probability-zero with distinct gumbel draws; keep
                        // lowest-index-wins via explicit compare
                        if (sc > bS[r] || (sc == bS[r] && (int)f < bI[r] && bS[r] > -1e29f)) {
                            bS[r] = sc; bI[r] = (int)f;
                        }
                    }
                }
            }
        }
    }

    // reduce best (val, idx) across wave, then across waves
#pragma unroll
    for (int r = 0; r < RROWS; ++r) {
        float v = bS[r]; int ix = bI[r];
#pragma unroll
        for (int off = 32; off; off >>= 1) {
            float ov = __shfl_xor(v, off);
            int   oi = __shfl_xor(ix, off);
            if (ov > v || (ov == v && oi < ix)) { v = ov; ix = oi; }
        }
        if (lane == 0) { redS[r][wv] = v; redI[r][wv] = ix; }
    }
    __syncthreads();
    if (t < RROWS) {
        float v = -1e30f; int ix = 0;
        for (int w = 0; w < 4; ++w) {
            float ov = redS[t][w]; int oi = redI[t][w];
            if (ov > v || (ov == v && oi < ix && ov > -1e29f)) { v = ov; ix = oi; }
        }
        rowInd[t] = ix & (FEATN - 1);   // hard guarantee: in-bounds gather
    }
    __syncthreads();

    // out[b,:] = codebook[ind,:]   (z_st == one-hot to ~1e-7)
    for (int r = 0; r < RROWS; ++r) {
        const int ind = rowInd[r];
        const float4* src = (const float4*)(codebook + (size_t)ind * FDIM);
        float4*       dst = (float4*)(out + (size_t)(b0 + r) * FDIM);
        dst[t] = src[t];
    }
}

// ---------------------------------------------------------------------------
extern "C" void kernel_launch(void* const* d_in, const int* in_sizes, int n_in,
                              void* d_out, int out_size, void* d_ws, size_t ws_size,
                              hipStream_t stream)
{
    const float* x   = (const float*)d_in[0];
    const float* y   = (const float*)d_in[1];
    const float* W1  = (const float*)d_in[2];
    const float* b1  = (const float*)d_in[3];
    const float* g1  = (const float*)d_in[4];
    const float* be1 = (const float*)d_in[5];
    const float* W2  = (const float*)d_in[6];
    const float* b2  = (const float*)d_in[7];
    const float* g2  = (const float*)d_in[8];
    const float* be2 = (const float*)d_in[9];
    const float* W3  = (const float*)d_in[10];
    const float* b3  = (const float*)d_in[11];
    const float* cb  = (const float*)d_in[12];
    float* out = (float*)d_out;

    float* ws  = (float*)d_ws;
    float* a1  = ws;                          // 8192*256 f32
    float* a2  = a1 + B_ROWS * H1;            // 8192*64 f32
    float* sc1 = a2 + B_ROWS * H2;
    float* sh1 = sc1 + H1;
    float* sc2 = sh1 + H1;
    float* sh2 = sc2 + H2;
    double* p1 = (double*)(sh2 + H2 + 64);    // 64*256 f64
    double* p2 = p1 + SLABS * H1;             // 64*256 f64

    k_a1    <<<B_ROWS / 8, 256, 0, stream>>>(x, y, W1, b1, a1);
    k_stats1<<<SLABS, 256, 0, stream>>>(a1, H1, p1, p2);
    k_stats2<<<H1, 64, 0, stream>>>(p1, p2, H1, g1, be1, sc1, sh1);
    k_a2    <<<B_ROWS / 4, 256, 0, stream>>>(a1, sc1, sh1, W2, b2, a2);
    k_stats1<<<SLABS, 256, 0, stream>>>(a2, H2, p1, p2);
    k_stats2<<<H2, 64, 0, stream>>>(p1, p2, H2, g2, be2, sc2, sh2);
    k_main  <<<B_ROWS / RROWS, 256, 0, stream>>>(a2, sc2, sh2, W3, b3, cb, out);
}